// Round 2
// baseline (73.460 us; speedup 1.0000x reference)
//
#include <hip/hip_runtime.h>
#include <math.h>

// Problem constants: N=8, L=8192, C=3
#define LEN 8192
#define NBATCH 8
#define NCH 3
#define BLK 256
#define PPT 4                         // points (l values) per thread
#define BPN (LEN / (BLK * PPT))       // 8 blocks per batch element
#define NBLOCKS (NBATCH * BPN)        // 64 blocks total
#define NQ 11

// Partial layout per block (part[b][q]):
//  q=0..2 : BCE sum, channel 0/1/2 (global over n,l)
//  q=3,4  : Σ x1, Σ x2            (per n)  -- proximity moments (input ch1,ch2)
//  q=5,6  : Σ x1², Σ x2²          (per n)
//  q=7,8  : sparsity sum input  ch1,ch2 (per n): Σ |d| - 0.5*max(d,0), d=x[l]-x[0]
//  q=9,10 : sparsity sum target ch1,ch2 (per n)

__device__ __forceinline__ float log_sigmoid(float x) {
    return fminf(x, 0.0f) - log1pf(expf(-fabsf(x)));
}

__device__ __forceinline__ float sp_term(float d) {
    return fabsf(d) - 0.5f * fmaxf(d, 0.0f);   // SPARSITY_B = 0.5
}

__global__ __launch_bounds__(BLK) void fused_kernel(
        const float* __restrict__ inp,
        const float* __restrict__ tgt,
        const float* __restrict__ cw,
        const float* __restrict__ pw,
        unsigned int* __restrict__ counter,
        float* __restrict__ part,
        float* __restrict__ out) {
    const int b = blockIdx.x;
    const int n = b >> 3;                               // 8 blocks per n
    const int l0 = (((b & 7) << 8) + threadIdx.x) * PPT;
    const float* ip = inp + (size_t)n * LEN * NCH;
    const float* tp = tgt + (size_t)n * LEN * NCH;

    // l=0 base values for sparsity diffs (wave-uniform -> broadcast)
    const float bi1 = ip[1], bi2 = ip[2];
    const float bt1 = tp[1], bt2 = tp[2];
    const float pw0 = pw[0], pw1 = pw[1], pw2 = pw[2];

    // 4 consecutive points = 12 floats = 3 x float4 (aligned: l0 % 4 == 0)
    const float4* i4 = reinterpret_cast<const float4*>(ip + (size_t)l0 * NCH);
    const float4* t4 = reinterpret_cast<const float4*>(tp + (size_t)l0 * NCH);
    const float4 ia = i4[0], ib = i4[1], ic = i4[2];
    const float4 ta = t4[0], tb = t4[1], tc = t4[2];

    const float xs[PPT][3] = {{ia.x, ia.y, ia.z}, {ia.w, ib.x, ib.y},
                              {ib.z, ib.w, ic.x}, {ic.y, ic.z, ic.w}};
    const float tss[PPT][3] = {{ta.x, ta.y, ta.z}, {ta.w, tb.x, tb.y},
                               {tb.z, tb.w, tc.x}, {tc.y, tc.z, tc.w}};

    float v[NQ];
#pragma unroll
    for (int q = 0; q < NQ; ++q) v[q] = 0.0f;

#pragma unroll
    for (int p = 0; p < PPT; ++p) {
        const float x0 = xs[p][0], x1 = xs[p][1], x2 = xs[p][2];
        const float t0 = tss[p][0], t1 = tss[p][1], t2 = tss[p][2];
        // bce = (1-t)*x - (pw*t + 1 - t) * log_sigmoid(x)
        // (uses log_sigmoid(-x) = log_sigmoid(x) - x; one transcendental per elem)
        v[0] += (1.0f - t0) * x0 - (pw0 * t0 + 1.0f - t0) * log_sigmoid(x0);
        v[1] += (1.0f - t1) * x1 - (pw1 * t1 + 1.0f - t1) * log_sigmoid(x1);
        v[2] += (1.0f - t2) * x2 - (pw2 * t2 + 1.0f - t2) * log_sigmoid(x2);
        v[3] += x1;
        v[4] += x2;
        v[5] += x1 * x1;
        v[6] += x2 * x2;
        // l==0 term is exactly 0, no branch needed
        v[7]  += sp_term(x1 - bi1);
        v[8]  += sp_term(x2 - bi2);
        v[9]  += sp_term(t1 - bt1);
        v[10] += sp_term(t2 - bt2);
    }

    // ---- block reduction: 64-lane shuffle tree, then LDS across the 4 waves
    __shared__ float red[4][NQ];
    const int lane = threadIdx.x & 63;
    const int wv   = threadIdx.x >> 6;
#pragma unroll
    for (int q = 0; q < NQ; ++q) {
        float s = v[q];
#pragma unroll
        for (int off = 32; off >= 1; off >>= 1) s += __shfl_down(s, off, 64);
        if (lane == 0) red[wv][q] = s;
    }
    __syncthreads();

    // ---- thread 0 publishes this block's partial row, then bumps the counter
    __shared__ int lastFlag;
    if (threadIdx.x == 0) {
#pragma unroll
        for (int q = 0; q < NQ; ++q)
            part[b * NQ + q] = red[0][q] + red[1][q] + red[2][q] + red[3][q];
        __threadfence();                       // release partials device-wide
        unsigned int old = atomicAdd(counter, 1u);
        lastFlag = (old == NBLOCKS - 1);
    }
    __syncthreads();
    if (!lastFlag) return;

    // ---- last block finalizes: 64 partial rows, wave 0 reduces them
    __threadfence();                            // acquire other blocks' stores
    __shared__ float bceS[3];
    __shared__ float perN[NBATCH][8];
    if (threadIdx.x < 64) {
        volatile const float* vp = part + threadIdx.x * NQ;  // bypass stale L1
        float r[NQ];
#pragma unroll
        for (int q = 0; q < NQ; ++q) r[q] = vp[q];
        // q=0..2: global reduce over all 64 rows
#pragma unroll
        for (int q = 0; q < 3; ++q) {
            float s = r[q];
#pragma unroll
            for (int off = 32; off >= 1; off >>= 1) s += __shfl_down(s, off, 64);
            if (threadIdx.x == 0) bceS[q] = s;
        }
        // q=3..10: segmented width-8 reduce (8 rows per batch element)
#pragma unroll
        for (int q = 3; q < NQ; ++q) {
            float s = r[q];
#pragma unroll
            for (int off = 4; off >= 1; off >>= 1) s += __shfl_down(s, off, 8);
            if ((threadIdx.x & 7) == 0) perN[threadIdx.x >> 3][q - 3] = s;
        }
    }
    __syncthreads();

    if (threadIdx.x == 0) {
        float loss = 0.0f;
        const float invNL = 1.0f / (float)(NBATCH * LEN);
#pragma unroll
        for (int c = 0; c < 3; ++c)
            loss += 10.0f * cw[c] * (bceS[c] * invNL);
#pragma unroll
        for (int n2 = 0; n2 < NBATCH; ++n2) {
            const float sum1 = perN[n2][0], sum2 = perN[n2][1];
            const float e1   = perN[n2][2], e2   = perN[n2][3];
            const float norm = sqrtf(e1 * e2);
            // mean(full cross-corr)/norm + penalty; Σcc = Σs1 * Σs2
            loss += (sum1 * sum2) / (norm * (float)(2 * LEN - 1))
                    + 1.0f - sqrtf(e1 + e2) / norm;
#pragma unroll
            for (int c = 0; c < 2; ++c) {
                const float si = 0.1f * perN[n2][4 + c];   // SPARSITY_A = 0.1
                const float st = 0.1f * perN[n2][6 + c];
                loss += fabsf(si - st) / (st + 1.0f);
            }
        }
        out[0] = loss;
    }
}

extern "C" void kernel_launch(void* const* d_in, const int* in_sizes, int n_in,
                              void* d_out, int out_size, void* d_ws, size_t ws_size,
                              hipStream_t stream) {
    const float* inp = (const float*)d_in[0];   // (N, L, C) f32
    const float* tgt = (const float*)d_in[1];   // (N, L, C) f32
    const float* cw  = (const float*)d_in[2];   // (C,) f32
    const float* pw  = (const float*)d_in[3];   // (C,) f32

    unsigned int* counter = (unsigned int*)d_ws;               // 4 bytes
    float* part = (float*)((char*)d_ws + 256);                 // 64*11 floats

    hipMemsetAsync(counter, 0, sizeof(unsigned int), stream);  // capture-safe
    fused_kernel<<<NBLOCKS, BLK, 0, stream>>>(inp, tgt, cw, pw,
                                              counter, part, (float*)d_out);
}

// Round 3
// 65.584 us; speedup vs baseline: 1.1201x; 1.1201x over previous
//
#include <hip/hip_runtime.h>
#include <math.h>

// Problem constants: N=8, L=8192, C=3
#define LEN 8192
#define NBATCH 8
#define NCH 3
#define ABLK 64                        // single wave per block -> no LDS, no barrier
#define PPT 4                          // points per thread
#define BPN (LEN / (ABLK * PPT))       // 32 blocks per batch element
#define NBLOCKS (NBATCH * BPN)         // 256 blocks
#define NQ 11

// part[b][q] layout:
//  q=0..2 : BCE sum, channel 0/1/2 (global over n,l)
//  q=3,4  : Σ x1, Σ x2              (per n)
//  q=5,6  : Σ x1², Σ x2²            (per n)
//  q=7,8  : sparsity sum input  ch1,ch2 (per n)
//  q=9,10 : sparsity sum target ch1,ch2 (per n)

__device__ __forceinline__ float log_sigmoid(float x) {
    return fminf(x, 0.0f) - log1pf(expf(-fabsf(x)));
}

__device__ __forceinline__ float sp_term(float d) {
    return fabsf(d) - 0.5f * fmaxf(d, 0.0f);   // SPARSITY_B = 0.5
}

__global__ __launch_bounds__(ABLK) void partial_kernel(
        const float* __restrict__ inp,
        const float* __restrict__ tgt,
        const float* __restrict__ pw,
        float* __restrict__ part) {
    const int b = blockIdx.x;
    const int n = b >> 5;                                // 32 blocks per n
    const int l0 = (((b & 31) << 6) + threadIdx.x) * PPT;
    const float* ip = inp + (size_t)n * LEN * NCH;
    const float* tp = tgt + (size_t)n * LEN * NCH;

    const float bi1 = ip[1], bi2 = ip[2];                // l=0 bases (broadcast)
    const float bt1 = tp[1], bt2 = tp[2];
    const float pw0 = pw[0], pw1 = pw[1], pw2 = pw[2];

    // 4 points = 12 floats = 3 x float4, aligned (l0 % 4 == 0)
    const float4* i4 = reinterpret_cast<const float4*>(ip + (size_t)l0 * NCH);
    const float4* t4 = reinterpret_cast<const float4*>(tp + (size_t)l0 * NCH);
    const float4 ia = i4[0], ib = i4[1], ic = i4[2];
    const float4 ta = t4[0], tb = t4[1], tc = t4[2];

    const float xs[PPT][3]  = {{ia.x, ia.y, ia.z}, {ia.w, ib.x, ib.y},
                               {ib.z, ib.w, ic.x}, {ic.y, ic.z, ic.w}};
    const float tss[PPT][3] = {{ta.x, ta.y, ta.z}, {ta.w, tb.x, tb.y},
                               {tb.z, tb.w, tc.x}, {tc.y, tc.z, tc.w}};

    float v[NQ];
#pragma unroll
    for (int q = 0; q < NQ; ++q) v[q] = 0.0f;

#pragma unroll
    for (int p = 0; p < PPT; ++p) {
        const float x0 = xs[p][0], x1 = xs[p][1], x2 = xs[p][2];
        const float t0 = tss[p][0], t1 = tss[p][1], t2 = tss[p][2];
        // bce = (1-t)*x - (pw*t + 1 - t)*log_sigmoid(x)   [logsig(-x)=logsig(x)-x]
        v[0] += (1.0f - t0) * x0 - (pw0 * t0 + 1.0f - t0) * log_sigmoid(x0);
        v[1] += (1.0f - t1) * x1 - (pw1 * t1 + 1.0f - t1) * log_sigmoid(x1);
        v[2] += (1.0f - t2) * x2 - (pw2 * t2 + 1.0f - t2) * log_sigmoid(x2);
        v[3] += x1;
        v[4] += x2;
        v[5] += x1 * x1;
        v[6] += x2 * x2;
        v[7]  += sp_term(x1 - bi1);      // l==0 term contributes exactly 0
        v[8]  += sp_term(x2 - bi2);
        v[9]  += sp_term(t1 - bt1);
        v[10] += sp_term(t2 - bt2);
    }

    // single-wave block: pure shuffle-tree reduce, no LDS, no barrier
#pragma unroll
    for (int q = 0; q < NQ; ++q) {
        float s = v[q];
#pragma unroll
        for (int off = 32; off >= 1; off >>= 1) s += __shfl_down(s, off, 64);
        v[q] = s;
    }
    if (threadIdx.x == 0) {
#pragma unroll
        for (int q = 0; q < NQ; ++q) part[b * NQ + q] = v[q];
    }
}

// One wave total. Lane j sums partial rows 4j..4j+3 (rows of one n stay within
// one 8-lane segment: 32 rows per n == 8 lanes per n).
__global__ __launch_bounds__(64) void finalize_kernel(
        const float* __restrict__ part,
        const float* __restrict__ cw,
        float* __restrict__ out) {
    const int lane = threadIdx.x;
    float r[NQ];
#pragma unroll
    for (int q = 0; q < NQ; ++q) {
        const float* p = part + (lane * 4) * NQ + q;
        r[q] = p[0] + p[NQ] + p[2 * NQ] + p[3 * NQ];
    }

    // q=0..2: full 64-lane reduce (result valid at lane 0)
    float bce0 = r[0], bce1 = r[1], bce2 = r[2];
#pragma unroll
    for (int off = 32; off >= 1; off >>= 1) {
        bce0 += __shfl_down(bce0, off, 64);
        bce1 += __shfl_down(bce1, off, 64);
        bce2 += __shfl_down(bce2, off, 64);
    }

    // q=3..10: segmented width-8 reduce (result valid at lanes 8n)
#pragma unroll
    for (int q = 3; q < NQ; ++q) {
#pragma unroll
        for (int off = 4; off >= 1; off >>= 1) r[q] += __shfl_down(r[q], off, 8);
    }

    // lanes 8n compute their batch element's proximity + sparsity contribution
    float c = 0.0f;
    if ((lane & 7) == 0) {
        const float sum1 = r[3], sum2 = r[4];
        const float e1 = r[5], e2 = r[6];
        const float norm = sqrtf(e1 * e2);
        c = (sum1 * sum2) / (norm * (float)(2 * LEN - 1))
            + 1.0f - sqrtf(e1 + e2) / norm;
#pragma unroll
        for (int ch = 0; ch < 2; ++ch) {
            const float si = 0.1f * r[7 + ch];    // SPARSITY_A = 0.1
            const float st = 0.1f * r[9 + ch];
            c += fabsf(si - st) / (st + 1.0f);
        }
    }
#pragma unroll
    for (int off = 32; off >= 1; off >>= 1) c += __shfl_down(c, off, 64);

    if (lane == 0) {
        const float invNL = 1.0f / (float)(NBATCH * LEN);
        float loss = 10.0f * (cw[0] * bce0 + cw[1] * bce1 + cw[2] * bce2) * invNL;
        out[0] = loss + c;
    }
}

extern "C" void kernel_launch(void* const* d_in, const int* in_sizes, int n_in,
                              void* d_out, int out_size, void* d_ws, size_t ws_size,
                              hipStream_t stream) {
    const float* inp = (const float*)d_in[0];   // (N, L, C) f32
    const float* tgt = (const float*)d_in[1];   // (N, L, C) f32
    const float* cw  = (const float*)d_in[2];   // (C,) f32
    const float* pw  = (const float*)d_in[3];   // (C,) f32
    float* part = (float*)d_ws;                 // NBLOCKS * NQ floats

    partial_kernel<<<NBLOCKS, ABLK, 0, stream>>>(inp, tgt, pw, part);
    finalize_kernel<<<1, 64, 0, stream>>>(part, cw, (float*)d_out);
}